// Round 20
// baseline (1976.550 us; speedup 1.0000x reference)
//
#include <hip/hip_runtime.h>
#include <hip/hip_bf16.h>
#include <stdint.h>

typedef __bf16 bf16;
typedef __attribute__((ext_vector_type(4))) float f32x4;
typedef __attribute__((ext_vector_type(8))) bf16 bf16x8;
typedef __attribute__((ext_vector_type(4))) bf16 bf16x4;

#define AS1 __attribute__((address_space(1)))
#define AS3 __attribute__((address_space(3)))

static __device__ __forceinline__ void gload_lds16(const bf16* g, bf16* l) {
  __builtin_amdgcn_global_load_lds((const AS1 void*)g, (AS3 void*)l, 16, 0, 0);
}

#define BAR __builtin_amdgcn_s_barrier()
#define SCHED0 __builtin_amdgcn_sched_barrier(0)
#define VMC_(n) asm volatile("s_waitcnt vmcnt(" #n ")" ::: "memory")
#define VMC(n) VMC_(n)
#define LGKM0 asm volatile("s_waitcnt lgkmcnt(0)" ::: "memory")

// ---- 256-thread staging (gemm_out only): one 128x64 bf16 tile ----
#define STAGE_A(gsrc, dst, kt_) do {                                          \
  _Pragma("unroll") for (int s_ = 0; s_ < 4; ++s_) {                          \
    int idx_ = s_ * 256 + tid;                                                \
    int r_ = idx_ >> 3, c_ = idx_ & 7;                                        \
    gload_lds16((gsrc) + (size_t)r_ * 512 + ((kt_) << 6) + ((c_ ^ (r_ & 7)) << 3), \
                (dst) + idx_ * 8);                                            \
  }                                                                           \
} while (0)

// B fragments from L2 (K-major bt[k/8][col][8]); 4 col-blocks (gemm_out)
#define LOADB(ktq, NCOLX) do {                                                \
  const bf16* bp_ = Bptr + (size_t)(ktq) * ((size_t)(NCOLX) * 64);            \
  _Pragma("unroll") for (int cb_ = 0; cb_ < 4; ++cb_)                         \
  _Pragma("unroll") for (int ks_ = 0; ks_ < 2; ++ks_)                         \
    bfr[cb_][ks_] = *(const bf16x8*)(bp_ + cb_ * 128 + (size_t)ks_ * (NCOLX) * 32); \
} while (0)

// gemm_out K-loop (round-6, verified)
#define KLOOP_BD(Ag, NCOLX)                                                   \
  f32x4 acc[4][4] = {};                                                       \
  bf16x8 af[4][2], bfr[4][2];                                                 \
  STAGE_A(Ag, SA0, 0);                                                        \
  LOADB(0, NCOLX);                                                            \
  VMC(8); BAR;                                                                \
  STAGE_A(Ag, SA1, 1);                                                        \
  _Pragma("unroll 2")                                                         \
  for (int kt = 0; kt < 8; ++kt) {                                            \
    bf16* Ap = (kt & 1) ? SA1 : SA0;                                          \
    _Pragma("unroll") for (int i_ = 0; i_ < 4; ++i_) {                        \
      int ra_ = wr + i_ * 16 + lr;                                            \
      _Pragma("unroll") for (int ks_ = 0; ks_ < 2; ++ks_)                     \
        af[i_][ks_] = *(const bf16x8*)(Ap + ra_ * 64 + (((ks_ * 4 + lg) ^ (ra_ & 7)) << 3)); \
    }                                                                         \
    LGKM0; SCHED0;                                                            \
    __builtin_amdgcn_s_setprio(1);                                            \
    _Pragma("unroll") for (int i_ = 0; i_ < 4; ++i_)                          \
    _Pragma("unroll") for (int j_ = 0; j_ < 4; ++j_)                          \
    _Pragma("unroll") for (int ks_ = 0; ks_ < 2; ++ks_)                       \
      acc[i_][j_] = __builtin_amdgcn_mfma_f32_16x16x32_bf16(                  \
          af[i_][ks_], bfr[j_][ks_], acc[i_][j_], 0, 0, 0);                   \
    __builtin_amdgcn_s_setprio(0);                                            \
    if (kt < 7) LOADB(kt + 1, NCOLX);                                         \
    if (kt < 7) { VMC(8); }                                                   \
    BAR;                                                                      \
    if (kt < 6) STAGE_A(Ag, Ap, kt + 2);                                      \
  }

// ---------------- merged prep (r15-verified) ----------------
__global__ __launch_bounds__(256) void prep_all(
    const float* __restrict__ x, const float* __restrict__ wqkv,
    const float* __restrict__ wout, const float* __restrict__ pos,
    bf16* __restrict__ xst, bf16* __restrict__ wqkv_bt,
    bf16* __restrict__ wout_bt, float* __restrict__ bias4) {
  const int blk = blockIdx.x, tid = threadIdx.x;
  if (blk < 1024) {
    int m = blk * 64 + (tid & 63);
    int w = tid >> 6;
    int b = m >> 12, win = (m >> 6) & 63, t = m & 63;
    int ip = ((win >> 3) << 3) + (t >> 3);
    int jp = ((win & 7) << 3) + (t & 7);
    int io = (ip + 4) & 63, jo = (jp + 4) & 63;
    const float* src = x + ((((size_t)(b << 6) + io) << 6) + jo) * 512;
    bf16* dst = xst + (size_t)m * 8;
    #pragma unroll
    for (int it = 0; it < 4; ++it) {
      int kb0 = w * 16 + it * 4;
      float4 v[8];
      #pragma unroll
      for (int q = 0; q < 8; ++q) v[q] = *(const float4*)(src + kb0 * 8 + q * 4);
      #pragma unroll
      for (int c = 0; c < 4; ++c) {
        bf16x8 o = { (bf16)v[2*c].x, (bf16)v[2*c].y, (bf16)v[2*c].z, (bf16)v[2*c].w,
                     (bf16)v[2*c+1].x, (bf16)v[2*c+1].y, (bf16)v[2*c+1].z, (bf16)v[2*c+1].w };
        *(bf16x8*)(dst + (size_t)(kb0 + c) * 524288) = o;
      }
    }
  } else if (blk < 1280) {
    int r = (blk - 1024) * 8 + (tid >> 5);
    int lane = tid & 31;
    if (r < 1536) {
      int part = r >> 9, h = (r >> 5) & 15, d = r & 31;
      int col = part * 32 + d;
      float sc = (part == 0) ? 0.17677669529663689f : 1.0f;
      const float* src = wqkv + (size_t)r * 512;
      #pragma unroll
      for (int kb = lane; kb < 64; kb += 32) {
        int kt = kb >> 3, ch = kb & 7;
        float4 v0 = *(const float4*)(src + kb * 8);
        float4 v1 = *(const float4*)(src + kb * 8 + 4);
        bf16x8 o = { (bf16)(v0.x * sc), (bf16)(v0.y * sc), (bf16)(v0.z * sc), (bf16)(v0.w * sc),
                     (bf16)(v1.x * sc), (bf16)(v1.y * sc), (bf16)(v1.z * sc), (bf16)(v1.w * sc) };
        *(bf16x8*)(wqkv_bt + (size_t)(h * 8 + kt) * 6144 + col * 64 + ((ch ^ (col & 7)) << 3)) = o;
      }
    } else {
      int r2 = r - 1536;
      const float* src = wout + (size_t)r2 * 512;
      #pragma unroll
      for (int kb = lane; kb < 64; kb += 32) {
        float4 v0 = *(const float4*)(src + kb * 8);
        float4 v1 = *(const float4*)(src + kb * 8 + 4);
        bf16x8 o = { (bf16)v0.x, (bf16)v0.y, (bf16)v0.z, (bf16)v0.w,
                     (bf16)v1.x, (bf16)v1.y, (bf16)v1.z, (bf16)v1.w };
        *(bf16x8*)(wout_bt + ((size_t)kb * 512 + r2) * 8) = o;
      }
    }
  } else {
    int idx = (blk - 1280) * 256 + tid;
    int ty = idx >> 12, ij = idx & 4095;
    int i = ij >> 6, j = ij & 63;
    int rx = ((j >> 3) - (i >> 3)) + 7;
    int ry = ((j & 7) - (i & 7)) + 7;
    float v = pos[rx * 15 + ry];
    if ((ty & 1) && (((i ^ j) >> 5) & 1)) v = -1e30f;
    if ((ty & 2) && (((i ^ j) >> 2) & 1)) v = -1e30f;
    bias4[idx] = v;
  }
}

// ---- qkv_attn: A streamed to regs (r12-verified), B shared via LDS dbuf ----
#define LOADAF(dst, ktq) do {                                                 \
  _Pragma("unroll") for (int i_ = 0; i_ < 2; ++i_)                            \
  _Pragma("unroll") for (int ks_ = 0; ks_ < 2; ++ks_)                         \
    dst[i_][ks_] = *(const bf16x8*)(Aptr + ((size_t)((ktq) * 8 + ks_ * 4 + lg)) * 524288 + i_ * 128); \
} while (0)

// Stage one (head,kt) 12KB B-image into LDS buffer: 3 gload_lds per thread.
#define STAGE_B(dstbuf, ktq) do {                                             \
  const bf16* src_ = Bh + (size_t)(ktq) * 6144;                               \
  _Pragma("unroll") for (int s_ = 0; s_ < 3; ++s_) {                          \
    int idx_ = s_ * 256 + tid;                                                \
    gload_lds16(src_ + idx_ * 8, (dstbuf) + idx_ * 8);                        \
  }                                                                           \
} while (0)

// Per-kt body. Per-thread FIFO ledger: enter kt with [A(kt):4, B(kt+1):3].
// issue A(kt+1) -> VMC(7) drains A(kt) -> MFMA -> VMC(4) drains B(kt+1)
// -> BAR publish -> stage B(kt+2) into the buffer just read.
// kt7: VMC(0); trailing BAR guards the E-union before the epilogue.
#define KTB(CUR, NXT, KT_) do {                                               \
  const bf16* Bp_ = smb + ((KT_) & 1) * 6144;                                 \
  _Pragma("unroll") for (int cb_ = 0; cb_ < 6; ++cb_)                         \
  _Pragma("unroll") for (int ks_ = 0; ks_ < 2; ++ks_) {                       \
    int col_ = cb_ * 16 + lr;                                                 \
    bfr[cb_][ks_] = *(const bf16x8*)(Bp_ + col_ * 64 + (((ks_ * 4 + lg) ^ (col_ & 7)) << 3)); \
  }                                                                           \
  if ((KT_) < 7) LOADAF(NXT, (KT_) + 1);                                      \
  if ((KT_) < 7) { VMC(7); } else { VMC(0); }                                 \
  LGKM0; SCHED0;                                                              \
  __builtin_amdgcn_s_setprio(1);                                              \
  _Pragma("unroll") for (int i_ = 0; i_ < 2; ++i_)                            \
  _Pragma("unroll") for (int j_ = 0; j_ < 6; ++j_)                            \
  _Pragma("unroll") for (int ks_ = 0; ks_ < 2; ++ks_)                         \
    acc[i_][j_] = __builtin_amdgcn_mfma_f32_16x16x32_bf16(                    \
        CUR[i_][ks_], bfr[j_][ks_], acc[i_][j_], 0, 0, 0);                    \
  __builtin_amdgcn_s_setprio(0);                                              \
  if ((KT_) < 7) { VMC(4); }                                                  \
  BAR;                                                                        \
  if ((KT_) < 6) STAGE_B(smb + ((KT_) & 1) * 6144, (KT_) + 2);                \
} while (0)

// ---------------- fused QKV-GEMM + window attention ----------------
// Block: 128 tokens (2 win x 2 row-halves) x 1 head; 4 waves.
// B: one 12KB LDS image per kt, staged ONCE per block. A: per-wave reg stream.
// LDS 24KB (B dbuf; E epilogue unions it).
// __launch_bounds__(256, 6): the r15/r19 kernel achieved VGPR=80 <= 512/6=85,
// and LDS permits 6 blocks/CU (144 <= 160KB) -- the old (256,3) declaration
// was the residency cap (Occ 31.7%, block latency ~15.6us vs ~3us of issue
// work => latency-wait). This doubles resident blocks at identical code.
__global__ __launch_bounds__(256, 6) void qkv_attn(
    const bf16* __restrict__ xst, const bf16* __restrict__ wb2,
    const float* __restrict__ bias4, bf16* __restrict__ ao) {
  __shared__ bf16 smb[12288];

  const int tid = threadIdx.x, wave = tid >> 6, lane = tid & 63;
  const int ww = wave >> 1, rh = wave & 1;     // window-in-tile, row-half
  const int lr = lane & 15, lg = lane >> 4;

  int bid = blockIdx.x;
  bid = (bid & 7) * 1024 + (bid >> 3);         // XCD swizzle (8192 = 8*1024)
  const int mt = bid >> 4, h = bid & 15;

  const bf16* Aptr = xst + ((size_t)(mt * 128 + ww * 64 + rh * 32 + lr)) * 8;
  const bf16* Bh = wb2 + (size_t)h * 49152;    // head's 8 kt-images (96KB)

  f32x4 acc[2][6] = {};
  bf16x8 afA[2][2], afB[2][2], bfr[6][2];

  // prologue: Bst(0):3 + A(0):4 -> VMC(4) drains B(0) -> BAR publish -> Bst(1)
  STAGE_B(smb, 0);
  LOADAF(afA, 0);
  VMC(4); BAR;
  STAGE_B(smb + 6144, 1);

  KTB(afA, afB, 0);
  KTB(afB, afA, 1);
  KTB(afA, afB, 2);
  KTB(afB, afA, 3);
  KTB(afA, afB, 4);
  KTB(afB, afA, 5);
  KTB(afA, afB, 6);
  KTB(afB, afA, 7);

  // ---- cross-wave epilogue (r11/r12-verified; kt7's BAR guards E reuse) ----
  bf16* Eu = smb + ww * 6144;                  // q|k [64][64] swizzled
  bf16* Ev = Eu + 4096;                        // vT [32][64] swizzled
  #pragma unroll
  for (int i = 0; i < 2; ++i)
    #pragma unroll
    for (int r = 0; r < 4; ++r) {
      int row = rh * 32 + i * 16 + (lg << 2) + r;
      #pragma unroll
      for (int j = 0; j < 4; ++j) {
        int c = j * 16 + lr;
        Eu[row * 64 + (c ^ ((row & 7) << 3))] = (bf16)acc[i][j][r];
      }
      #pragma unroll
      for (int j = 4; j < 6; ++j) {
        int cv = (j - 4) * 16 + lr;
        Ev[cv * 64 + (row ^ ((cv & 7) << 3))] = (bf16)acc[i][j][r];
      }
    }
  LGKM0; BAR;                                  // publish q|k|vT to pair wave

  bf16x8 qf[2], kf[4];
  #pragma unroll
  for (int i = 0; i < 2; ++i) {
    int ra = rh * 32 + i * 16 + lr;
    qf[i] = *(const bf16x8*)(Eu + ra * 64 + ((lg << 3) ^ ((ra & 7) << 3)));
  }
  #pragma unroll
  for (int j = 0; j < 4; ++j) {
    int rb = j * 16 + lr;
    kf[j] = *(const bf16x8*)(Eu + rb * 64 + ((32 + (lg << 3)) ^ ((rb & 7) << 3)));
  }
  f32x4 s[2][4] = {};
  #pragma unroll
  for (int i = 0; i < 2; ++i)
    #pragma unroll
    for (int j = 0; j < 4; ++j)
      s[i][j] = __builtin_amdgcn_mfma_f32_16x16x32_bf16(qf[i], kf[j], s[i][j], 0, 0, 0);

  const int gw = mt * 2 + ww;
  const int win = gw & 63;
  const int ty = ((win >= 56) ? 1 : 0) | (((win & 7) == 7) ? 2 : 0);
  const float* bt = bias4 + ty * 4096;
  #pragma unroll
  for (int i = 0; i < 2; ++i)
    #pragma unroll
    for (int r = 0; r < 4; ++r) {
      int grow = rh * 32 + i * 16 + (lg << 2) + r;
      #pragma unroll
      for (int j = 0; j < 4; ++j)
        s[i][j][r] += bt[grow * 64 + j * 16 + lr];
    }
  #pragma unroll
  for (int i = 0; i < 2; ++i)
    #pragma unroll
    for (int r = 0; r < 4; ++r) {
      float mx = fmaxf(fmaxf(s[i][0][r], s[i][1][r]), fmaxf(s[i][2][r], s[i][3][r]));
      mx = fmaxf(mx, __shfl_xor(mx, 1));
      mx = fmaxf(mx, __shfl_xor(mx, 2));
      mx = fmaxf(mx, __shfl_xor(mx, 4));
      mx = fmaxf(mx, __shfl_xor(mx, 8));
      float sum = 0.f;
      #pragma unroll
      for (int j = 0; j < 4; ++j) { s[i][j][r] = __expf(s[i][j][r] - mx); sum += s[i][j][r]; }
      sum += __shfl_xor(sum, 1);
      sum += __shfl_xor(sum, 2);
      sum += __shfl_xor(sum, 4);
      sum += __shfl_xor(sum, 8);
      float inv = 1.0f / sum;
      #pragma unroll
      for (int j = 0; j < 4; ++j) s[i][j][r] *= inv;
    }
  BAR;                                         // pair's kf reads done before P overwrite
  #pragma unroll
  for (int i = 0; i < 2; ++i)
    #pragma unroll
    for (int r = 0; r < 4; ++r) {
      int row = rh * 32 + i * 16 + (lg << 2) + r;
      #pragma unroll
      for (int j = 0; j < 4; ++j) {
        int c = j * 16 + lr;
        Eu[row * 64 + (c ^ ((row & 7) << 3))] = (bf16)s[i][j][r];
      }
    }
  LGKM0; SCHED0;
  bf16x8 vf[2][2];
  #pragma unroll
  for (int kk = 0; kk < 2; ++kk)
    #pragma unroll
    for (int nj = 0; nj < 2; ++nj) {
      int dv = nj * 16 + lr;
      vf[kk][nj] = *(const bf16x8*)(Ev + dv * 64 + ((kk * 32 + (lg << 3)) ^ ((dv & 7) << 3)));
    }
  f32x4 o[2][2] = {};
  #pragma unroll
  for (int kk = 0; kk < 2; ++kk)
    #pragma unroll
    for (int mi = 0; mi < 2; ++mi) {
      int ra = rh * 32 + mi * 16 + lr;
      bf16x8 pa = *(const bf16x8*)(Eu + ra * 64 + ((kk * 32 + (lg << 3)) ^ ((ra & 7) << 3)));
      #pragma unroll
      for (int nj = 0; nj < 2; ++nj)
        o[mi][nj] = __builtin_amdgcn_mfma_f32_16x16x32_bf16(pa, vf[kk][nj], o[mi][nj], 0, 0, 0);
    }
  bf16* dst = ao + ((size_t)(mt * 128 + ww * 64)) * 512 + h * 32;
  #pragma unroll
  for (int mi = 0; mi < 2; ++mi)
    #pragma unroll
    for (int r = 0; r < 4; ++r) {
      int t = rh * 32 + mi * 16 + (lg << 2) + r;
      #pragma unroll
      for (int nj = 0; nj < 2; ++nj)
        dst[(size_t)t * 512 + nj * 16 + lr] = (bf16)o[mi][nj][r];
    }
}

// ---------------- out-proj GEMM + bias + inverse roll ----------------
// (256,5): achieved VGPR ~84-92 <= 512/5=102; LDS 32KB caps at 5 blocks/CU.
__global__ __launch_bounds__(256, 5) void gemm_out(
    const bf16* __restrict__ ao, const bf16* __restrict__ wob,
    const float* __restrict__ bout, float* __restrict__ out) {
  __shared__ bf16 SA[2][8192];
  bf16* SA0 = SA[0]; bf16* SA1 = SA[1];

  const int tid = threadIdx.x, wave = tid >> 6, lane = tid & 63;
  int bid = blockIdx.x;
  bid = (bid & 7) * 256 + (bid >> 3);          // XCD swizzle (2048 = 8*256)
  const int mt = bid >> 2, nt = bid & 3;
  const bf16* Ag = ao + ((size_t)mt * 128) * 512;
  const int wr = (wave >> 1) << 6, wc = (wave & 1) << 6;
  const int lr = lane & 15, lg = lane >> 4;
  const bf16* Bptr = wob + (((size_t)lg * 512) + nt * 128 + wc + lr) * 8;

  KLOOP_BD(Ag, 512)

  float bv[4];
  #pragma unroll
  for (int j = 0; j < 4; ++j) bv[j] = bout[nt * 128 + wc + j * 16 + lr];
  #pragma unroll
  for (int i = 0; i < 4; ++i)
    #pragma unroll
    for (int r = 0; r < 4; ++r) {
      int m = (mt << 7) + wr + i * 16 + (lg << 2) + r;
      int b = m >> 12, win = (m >> 6) & 63, t = m & 63;
      int ip = ((win >> 3) << 3) + (t >> 3);
      int jp = ((win & 7) << 3) + (t & 7);
      int io = (ip + 4) & 63, jo = (jp + 4) & 63;
      float* orow = out + ((((size_t)(b << 6) + io) << 6) + jo) * 512 + nt * 128 + wc;
      #pragma unroll
      for (int j = 0; j < 4; ++j)
        orow[j * 16 + lr] = acc[i][j][r] + bv[j];
    }
}

extern "C" void kernel_launch(void* const* d_in, const int* in_sizes, int n_in,
                              void* d_out, int out_size, void* d_ws, size_t ws_size,
                              hipStream_t stream) {
  const float* x    = (const float*)d_in[0];
  const float* wqkv = (const float*)d_in[1];
  const float* pos  = (const float*)d_in[2];
  const float* wout = (const float*)d_in[3];
  const float* bout = (const float*)d_in[4];
  float* out = (float*)d_out;

  char* ws = (char*)d_ws;
  bf16* xst     = (bf16*)(ws);                 // 64 MB (K-major)
  bf16* ao      = (bf16*)(ws + 67108864);      // 64 MB
  bf16* wqkv_bt = (bf16*)(ws + 268435456);     // 1.5 MB (per-(h,kt) LDS images)
  bf16* wout_bt = (bf16*)(ws + 270008320);
  float* bias4  = (float*)(ws + 270532608);

  prep_all<<<dim3(1344), dim3(256), 0, stream>>>(x, wqkv, wout, pos,
                                                 xst, wqkv_bt, wout_bt, bias4);
  qkv_attn<<<dim3(8192), dim3(256), 0, stream>>>(xst, wqkv_bt, bias4, ao);
  gemm_out<<<dim3(2048), dim3(256), 0, stream>>>(ao, wout_bt, bout, out);
}

// Round 21
// 246.476 us; speedup vs baseline: 8.0192x; 8.0192x over previous
//
#include <hip/hip_runtime.h>
#include <hip/hip_bf16.h>
#include <stdint.h>

typedef __bf16 bf16;
typedef __attribute__((ext_vector_type(4))) float f32x4;
typedef __attribute__((ext_vector_type(8))) bf16 bf16x8;
typedef __attribute__((ext_vector_type(4))) bf16 bf16x4;

#define AS1 __attribute__((address_space(1)))
#define AS3 __attribute__((address_space(3)))

static __device__ __forceinline__ void gload_lds16(const bf16* g, bf16* l) {
  __builtin_amdgcn_global_load_lds((const AS1 void*)g, (AS3 void*)l, 16, 0, 0);
}

#define BAR __builtin_amdgcn_s_barrier()
#define SCHED0 __builtin_amdgcn_sched_barrier(0)
#define VMC_(n) asm volatile("s_waitcnt vmcnt(" #n ")" ::: "memory")
#define VMC(n) VMC_(n)
#define LGKM0 asm volatile("s_waitcnt lgkmcnt(0)" ::: "memory")

// ---- 256-thread staging (gemm_out only): one 128x64 bf16 tile ----
#define STAGE_A(gsrc, dst, kt_) do {                                          \
  _Pragma("unroll") for (int s_ = 0; s_ < 4; ++s_) {                          \
    int idx_ = s_ * 256 + tid;                                                \
    int r_ = idx_ >> 3, c_ = idx_ & 7;                                        \
    gload_lds16((gsrc) + (size_t)r_ * 512 + ((kt_) << 6) + ((c_ ^ (r_ & 7)) << 3), \
                (dst) + idx_ * 8);                                            \
  }                                                                           \
} while (0)

// B fragments from L2 (K-major bt[k/8][col][8]); 4 col-blocks (gemm_out)
#define LOADB(ktq, NCOLX) do {                                                \
  const bf16* bp_ = Bptr + (size_t)(ktq) * ((size_t)(NCOLX) * 64);            \
  _Pragma("unroll") for (int cb_ = 0; cb_ < 4; ++cb_)                         \
  _Pragma("unroll") for (int ks_ = 0; ks_ < 2; ++ks_)                         \
    bfr[cb_][ks_] = *(const bf16x8*)(bp_ + cb_ * 128 + (size_t)ks_ * (NCOLX) * 32); \
} while (0)

// gemm_out K-loop (round-6, verified)
#define KLOOP_BD(Ag, NCOLX)                                                   \
  f32x4 acc[4][4] = {};                                                       \
  bf16x8 af[4][2], bfr[4][2];                                                 \
  STAGE_A(Ag, SA0, 0);                                                        \
  LOADB(0, NCOLX);                                                            \
  VMC(8); BAR;                                                                \
  STAGE_A(Ag, SA1, 1);                                                        \
  _Pragma("unroll 2")                                                         \
  for (int kt = 0; kt < 8; ++kt) {                                            \
    bf16* Ap = (kt & 1) ? SA1 : SA0;                                          \
    _Pragma("unroll") for (int i_ = 0; i_ < 4; ++i_) {                        \
      int ra_ = wr + i_ * 16 + lr;                                            \
      _Pragma("unroll") for (int ks_ = 0; ks_ < 2; ++ks_)                     \
        af[i_][ks_] = *(const bf16x8*)(Ap + ra_ * 64 + (((ks_ * 4 + lg) ^ (ra_ & 7)) << 3)); \
    }                                                                         \
    LGKM0; SCHED0;                                                            \
    __builtin_amdgcn_s_setprio(1);                                            \
    _Pragma("unroll") for (int i_ = 0; i_ < 4; ++i_)                          \
    _Pragma("unroll") for (int j_ = 0; j_ < 4; ++j_)                          \
    _Pragma("unroll") for (int ks_ = 0; ks_ < 2; ++ks_)                       \
      acc[i_][j_] = __builtin_amdgcn_mfma_f32_16x16x32_bf16(                  \
          af[i_][ks_], bfr[j_][ks_], acc[i_][j_], 0, 0, 0);                   \
    __builtin_amdgcn_s_setprio(0);                                            \
    if (kt < 7) LOADB(kt + 1, NCOLX);                                         \
    if (kt < 7) { VMC(8); }                                                   \
    BAR;                                                                      \
    if (kt < 6) STAGE_A(Ag, Ap, kt + 2);                                      \
  }

// ---------------- merged prep (r15-verified) ----------------
__global__ __launch_bounds__(256) void prep_all(
    const float* __restrict__ x, const float* __restrict__ wqkv,
    const float* __restrict__ wout, const float* __restrict__ pos,
    bf16* __restrict__ xst, bf16* __restrict__ wqkv_bt,
    bf16* __restrict__ wout_bt, float* __restrict__ bias4) {
  const int blk = blockIdx.x, tid = threadIdx.x;
  if (blk < 1024) {
    int m = blk * 64 + (tid & 63);
    int w = tid >> 6;
    int b = m >> 12, win = (m >> 6) & 63, t = m & 63;
    int ip = ((win >> 3) << 3) + (t >> 3);
    int jp = ((win & 7) << 3) + (t & 7);
    int io = (ip + 4) & 63, jo = (jp + 4) & 63;
    const float* src = x + ((((size_t)(b << 6) + io) << 6) + jo) * 512;
    bf16* dst = xst + (size_t)m * 8;
    #pragma unroll
    for (int it = 0; it < 4; ++it) {
      int kb0 = w * 16 + it * 4;
      float4 v[8];
      #pragma unroll
      for (int q = 0; q < 8; ++q) v[q] = *(const float4*)(src + kb0 * 8 + q * 4);
      #pragma unroll
      for (int c = 0; c < 4; ++c) {
        bf16x8 o = { (bf16)v[2*c].x, (bf16)v[2*c].y, (bf16)v[2*c].z, (bf16)v[2*c].w,
                     (bf16)v[2*c+1].x, (bf16)v[2*c+1].y, (bf16)v[2*c+1].z, (bf16)v[2*c+1].w };
        *(bf16x8*)(dst + (size_t)(kb0 + c) * 524288) = o;
      }
    }
  } else if (blk < 1280) {
    int r = (blk - 1024) * 8 + (tid >> 5);
    int lane = tid & 31;
    if (r < 1536) {
      int part = r >> 9, h = (r >> 5) & 15, d = r & 31;
      int col = part * 32 + d;
      float sc = (part == 0) ? 0.17677669529663689f : 1.0f;
      const float* src = wqkv + (size_t)r * 512;
      #pragma unroll
      for (int kb = lane; kb < 64; kb += 32) {
        int kt = kb >> 3, ch = kb & 7;
        float4 v0 = *(const float4*)(src + kb * 8);
        float4 v1 = *(const float4*)(src + kb * 8 + 4);
        bf16x8 o = { (bf16)(v0.x * sc), (bf16)(v0.y * sc), (bf16)(v0.z * sc), (bf16)(v0.w * sc),
                     (bf16)(v1.x * sc), (bf16)(v1.y * sc), (bf16)(v1.z * sc), (bf16)(v1.w * sc) };
        *(bf16x8*)(wqkv_bt + (size_t)(h * 8 + kt) * 6144 + col * 64 + ((ch ^ (col & 7)) << 3)) = o;
      }
    } else {
      int r2 = r - 1536;
      const float* src = wout + (size_t)r2 * 512;
      #pragma unroll
      for (int kb = lane; kb < 64; kb += 32) {
        float4 v0 = *(const float4*)(src + kb * 8);
        float4 v1 = *(const float4*)(src + kb * 8 + 4);
        bf16x8 o = { (bf16)v0.x, (bf16)v0.y, (bf16)v0.z, (bf16)v0.w,
                     (bf16)v1.x, (bf16)v1.y, (bf16)v1.z, (bf16)v1.w };
        *(bf16x8*)(wout_bt + ((size_t)kb * 512 + r2) * 8) = o;
      }
    }
  } else {
    int idx = (blk - 1280) * 256 + tid;
    int ty = idx >> 12, ij = idx & 4095;
    int i = ij >> 6, j = ij & 63;
    int rx = ((j >> 3) - (i >> 3)) + 7;
    int ry = ((j & 7) - (i & 7)) + 7;
    float v = pos[rx * 15 + ry];
    if ((ty & 1) && (((i ^ j) >> 5) & 1)) v = -1e30f;
    if ((ty & 2) && (((i ^ j) >> 2) & 1)) v = -1e30f;
    bias4[idx] = v;
  }
}

// ---- qkv_attn: A streamed to regs (r12-verified), B shared via LDS dbuf ----
#define LOADAF(dst, ktq) do {                                                 \
  _Pragma("unroll") for (int i_ = 0; i_ < 2; ++i_)                            \
  _Pragma("unroll") for (int ks_ = 0; ks_ < 2; ++ks_)                         \
    dst[i_][ks_] = *(const bf16x8*)(Aptr + ((size_t)((ktq) * 8 + ks_ * 4 + lg)) * 524288 + i_ * 128); \
} while (0)

// Stage one (head,kt) 12KB B-image into LDS buffer: 3 gload_lds per thread.
#define STAGE_B(dstbuf, ktq) do {                                             \
  const bf16* src_ = Bh + (size_t)(ktq) * 6144;                               \
  _Pragma("unroll") for (int s_ = 0; s_ < 3; ++s_) {                          \
    int idx_ = s_ * 256 + tid;                                                \
    gload_lds16(src_ + idx_ * 8, (dstbuf) + idx_ * 8);                        \
  }                                                                           \
} while (0)

// Per-kt body. Per-thread FIFO ledger: enter kt with [A(kt):4, B(kt+1):3].
// issue A(kt+1) -> VMC(7) drains A(kt) -> MFMA -> VMC(4) drains B(kt+1)
// -> BAR publish -> stage B(kt+2) into the buffer just read.
// kt7: VMC(0); trailing BAR guards the E-union before the epilogue.
#define KTB(CUR, NXT, KT_) do {                                               \
  const bf16* Bp_ = smb + ((KT_) & 1) * 6144;                                 \
  _Pragma("unroll") for (int cb_ = 0; cb_ < 6; ++cb_)                         \
  _Pragma("unroll") for (int ks_ = 0; ks_ < 2; ++ks_) {                       \
    int col_ = cb_ * 16 + lr;                                                 \
    bfr[cb_][ks_] = *(const bf16x8*)(Bp_ + col_ * 64 + (((ks_ * 4 + lg) ^ (col_ & 7)) << 3)); \
  }                                                                           \
  if ((KT_) < 7) LOADAF(NXT, (KT_) + 1);                                      \
  if ((KT_) < 7) { VMC(7); } else { VMC(0); }                                 \
  LGKM0; SCHED0;                                                              \
  __builtin_amdgcn_s_setprio(1);                                              \
  _Pragma("unroll") for (int i_ = 0; i_ < 2; ++i_)                            \
  _Pragma("unroll") for (int j_ = 0; j_ < 6; ++j_)                            \
  _Pragma("unroll") for (int ks_ = 0; ks_ < 2; ++ks_)                         \
    acc[i_][j_] = __builtin_amdgcn_mfma_f32_16x16x32_bf16(                    \
        CUR[i_][ks_], bfr[j_][ks_], acc[i_][j_], 0, 0, 0);                    \
  __builtin_amdgcn_s_setprio(0);                                              \
  if ((KT_) < 7) { VMC(4); }                                                  \
  BAR;                                                                        \
  if ((KT_) < 6) STAGE_B(smb + ((KT_) & 1) * 6144, (KT_) + 2);                \
} while (0)

// ---------------- fused QKV-GEMM + window attention ----------------
// Block: 128 tokens (2 win x 2 row-halves) x 1 head; 4 waves.
// B: one 12KB LDS image per kt, staged ONCE per block. A: per-wave reg stream.
// LDS 24KB (B dbuf; E epilogue unions it). (256,3) -> achieved VGPR 80,
// 3 waves/SIMD bucket. MEASURED OPTIMUM (r15: 247.5us, r19: 246.8us total).
// Falsified alternatives: (256,6)->spill (r20, VGPR 40, 1436us);
// 256-token blocks (r18: 197us); depth-2 (r13); all-LDS (r2-r5);
// pure-stream (r12: 179us before B-dedup).
__global__ __launch_bounds__(256, 3) void qkv_attn(
    const bf16* __restrict__ xst, const bf16* __restrict__ wb2,
    const float* __restrict__ bias4, bf16* __restrict__ ao) {
  __shared__ bf16 smb[12288];

  const int tid = threadIdx.x, wave = tid >> 6, lane = tid & 63;
  const int ww = wave >> 1, rh = wave & 1;     // window-in-tile, row-half
  const int lr = lane & 15, lg = lane >> 4;

  int bid = blockIdx.x;
  bid = (bid & 7) * 1024 + (bid >> 3);         // XCD swizzle (8192 = 8*1024)
  const int mt = bid >> 4, h = bid & 15;

  const bf16* Aptr = xst + ((size_t)(mt * 128 + ww * 64 + rh * 32 + lr)) * 8;
  const bf16* Bh = wb2 + (size_t)h * 49152;    // head's 8 kt-images (96KB)

  f32x4 acc[2][6] = {};
  bf16x8 afA[2][2], afB[2][2], bfr[6][2];

  // prologue: Bst(0):3 + A(0):4 -> VMC(4) drains B(0) -> BAR publish -> Bst(1)
  STAGE_B(smb, 0);
  LOADAF(afA, 0);
  VMC(4); BAR;
  STAGE_B(smb + 6144, 1);

  KTB(afA, afB, 0);
  KTB(afB, afA, 1);
  KTB(afA, afB, 2);
  KTB(afB, afA, 3);
  KTB(afA, afB, 4);
  KTB(afB, afA, 5);
  KTB(afA, afB, 6);
  KTB(afB, afA, 7);

  // ---- cross-wave epilogue (r11/r12-verified; kt7's BAR guards E reuse) ----
  bf16* Eu = smb + ww * 6144;                  // q|k [64][64] swizzled
  bf16* Ev = Eu + 4096;                        // vT [32][64] swizzled
  #pragma unroll
  for (int i = 0; i < 2; ++i)
    #pragma unroll
    for (int r = 0; r < 4; ++r) {
      int row = rh * 32 + i * 16 + (lg << 2) + r;
      #pragma unroll
      for (int j = 0; j < 4; ++j) {
        int c = j * 16 + lr;
        Eu[row * 64 + (c ^ ((row & 7) << 3))] = (bf16)acc[i][j][r];
      }
      #pragma unroll
      for (int j = 4; j < 6; ++j) {
        int cv = (j - 4) * 16 + lr;
        Ev[cv * 64 + (row ^ ((cv & 7) << 3))] = (bf16)acc[i][j][r];
      }
    }
  LGKM0; BAR;                                  // publish q|k|vT to pair wave

  bf16x8 qf[2], kf[4];
  #pragma unroll
  for (int i = 0; i < 2; ++i) {
    int ra = rh * 32 + i * 16 + lr;
    qf[i] = *(const bf16x8*)(Eu + ra * 64 + ((lg << 3) ^ ((ra & 7) << 3)));
  }
  #pragma unroll
  for (int j = 0; j < 4; ++j) {
    int rb = j * 16 + lr;
    kf[j] = *(const bf16x8*)(Eu + rb * 64 + ((32 + (lg << 3)) ^ ((rb & 7) << 3)));
  }
  f32x4 s[2][4] = {};
  #pragma unroll
  for (int i = 0; i < 2; ++i)
    #pragma unroll
    for (int j = 0; j < 4; ++j)
      s[i][j] = __builtin_amdgcn_mfma_f32_16x16x32_bf16(qf[i], kf[j], s[i][j], 0, 0, 0);

  const int gw = mt * 2 + ww;
  const int win = gw & 63;
  const int ty = ((win >= 56) ? 1 : 0) | (((win & 7) == 7) ? 2 : 0);
  const float* bt = bias4 + ty * 4096;
  #pragma unroll
  for (int i = 0; i < 2; ++i)
    #pragma unroll
    for (int r = 0; r < 4; ++r) {
      int grow = rh * 32 + i * 16 + (lg << 2) + r;
      #pragma unroll
      for (int j = 0; j < 4; ++j)
        s[i][j][r] += bt[grow * 64 + j * 16 + lr];
    }
  #pragma unroll
  for (int i = 0; i < 2; ++i)
    #pragma unroll
    for (int r = 0; r < 4; ++r) {
      float mx = fmaxf(fmaxf(s[i][0][r], s[i][1][r]), fmaxf(s[i][2][r], s[i][3][r]));
      mx = fmaxf(mx, __shfl_xor(mx, 1));
      mx = fmaxf(mx, __shfl_xor(mx, 2));
      mx = fmaxf(mx, __shfl_xor(mx, 4));
      mx = fmaxf(mx, __shfl_xor(mx, 8));
      float sum = 0.f;
      #pragma unroll
      for (int j = 0; j < 4; ++j) { s[i][j][r] = __expf(s[i][j][r] - mx); sum += s[i][j][r]; }
      sum += __shfl_xor(sum, 1);
      sum += __shfl_xor(sum, 2);
      sum += __shfl_xor(sum, 4);
      sum += __shfl_xor(sum, 8);
      float inv = 1.0f / sum;
      #pragma unroll
      for (int j = 0; j < 4; ++j) s[i][j][r] *= inv;
    }
  BAR;                                         // pair's kf reads done before P overwrite
  #pragma unroll
  for (int i = 0; i < 2; ++i)
    #pragma unroll
    for (int r = 0; r < 4; ++r) {
      int row = rh * 32 + i * 16 + (lg << 2) + r;
      #pragma unroll
      for (int j = 0; j < 4; ++j) {
        int c = j * 16 + lr;
        Eu[row * 64 + (c ^ ((row & 7) << 3))] = (bf16)s[i][j][r];
      }
    }
  LGKM0; SCHED0;
  bf16x8 vf[2][2];
  #pragma unroll
  for (int kk = 0; kk < 2; ++kk)
    #pragma unroll
    for (int nj = 0; nj < 2; ++nj) {
      int dv = nj * 16 + lr;
      vf[kk][nj] = *(const bf16x8*)(Ev + dv * 64 + ((kk * 32 + (lg << 3)) ^ ((dv & 7) << 3)));
    }
  f32x4 o[2][2] = {};
  #pragma unroll
  for (int kk = 0; kk < 2; ++kk)
    #pragma unroll
    for (int mi = 0; mi < 2; ++mi) {
      int ra = rh * 32 + mi * 16 + lr;
      bf16x8 pa = *(const bf16x8*)(Eu + ra * 64 + ((kk * 32 + (lg << 3)) ^ ((ra & 7) << 3)));
      #pragma unroll
      for (int nj = 0; nj < 2; ++nj)
        o[mi][nj] = __builtin_amdgcn_mfma_f32_16x16x32_bf16(pa, vf[kk][nj], o[mi][nj], 0, 0, 0);
    }
  bf16* dst = ao + ((size_t)(mt * 128 + ww * 64)) * 512 + h * 32;
  #pragma unroll
  for (int mi = 0; mi < 2; ++mi)
    #pragma unroll
    for (int r = 0; r < 4; ++r) {
      int t = rh * 32 + mi * 16 + (lg << 2) + r;
      #pragma unroll
      for (int nj = 0; nj < 2; ++nj)
        dst[(size_t)t * 512 + nj * 16 + lr] = (bf16)o[mi][nj][r];
    }
}

// ---------------- out-proj GEMM + bias + inverse roll ----------------
__global__ __launch_bounds__(256, 3) void gemm_out(
    const bf16* __restrict__ ao, const bf16* __restrict__ wob,
    const float* __restrict__ bout, float* __restrict__ out) {
  __shared__ bf16 SA[2][8192];
  bf16* SA0 = SA[0]; bf16* SA1 = SA[1];

  const int tid = threadIdx.x, wave = tid >> 6, lane = tid & 63;
  int bid = blockIdx.x;
  bid = (bid & 7) * 256 + (bid >> 3);          // XCD swizzle (2048 = 8*256)
  const int mt = bid >> 2, nt = bid & 3;
  const bf16* Ag = ao + ((size_t)mt * 128) * 512;
  const int wr = (wave >> 1) << 6, wc = (wave & 1) << 6;
  const int lr = lane & 15, lg = lane >> 4;
  const bf16* Bptr = wob + (((size_t)lg * 512) + nt * 128 + wc + lr) * 8;

  KLOOP_BD(Ag, 512)

  float bv[4];
  #pragma unroll
  for (int j = 0; j < 4; ++j) bv[j] = bout[nt * 128 + wc + j * 16 + lr];
  #pragma unroll
  for (int i = 0; i < 4; ++i)
    #pragma unroll
    for (int r = 0; r < 4; ++r) {
      int m = (mt << 7) + wr + i * 16 + (lg << 2) + r;
      int b = m >> 12, win = (m >> 6) & 63, t = m & 63;
      int ip = ((win >> 3) << 3) + (t >> 3);
      int jp = ((win & 7) << 3) + (t & 7);
      int io = (ip + 4) & 63, jo = (jp + 4) & 63;
      float* orow = out + ((((size_t)(b << 6) + io) << 6) + jo) * 512 + nt * 128 + wc;
      #pragma unroll
      for (int j = 0; j < 4; ++j)
        orow[j * 16 + lr] = acc[i][j][r] + bv[j];
    }
}

extern "C" void kernel_launch(void* const* d_in, const int* in_sizes, int n_in,
                              void* d_out, int out_size, void* d_ws, size_t ws_size,
                              hipStream_t stream) {
  const float* x    = (const float*)d_in[0];
  const float* wqkv = (const float*)d_in[1];
  const float* pos  = (const float*)d_in[2];
  const float* wout = (const float*)d_in[3];
  const float* bout = (const float*)d_in[4];
  float* out = (float*)d_out;

  char* ws = (char*)d_ws;
  bf16* xst     = (bf16*)(ws);                 // 64 MB (K-major)
  bf16* ao      = (bf16*)(ws + 67108864);      // 64 MB
  bf16* wqkv_bt = (bf16*)(ws + 268435456);     // 1.5 MB (per-(h,kt) LDS images)
  bf16* wout_bt = (bf16*)(ws + 270008320);
  float* bias4  = (float*)(ws + 270532608);

  prep_all<<<dim3(1344), dim3(256), 0, stream>>>(x, wqkv, wout, pos,
                                                 xst, wqkv_bt, wout_bt, bias4);
  qkv_attn<<<dim3(8192), dim3(256), 0, stream>>>(xst, wqkv_bt, bias4, ao);
  gemm_out<<<dim3(2048), dim3(256), 0, stream>>>(ao, wout_bt, bout, out);
}